// Round 1
// baseline (183.487 us; speedup 1.0000x reference)
//
#include <hip/hip_runtime.h>
#include <math.h>

// Problem constants (fixed by the reference):
#define BB 32     // batch
#define NN 128    // nodes
#define CC 16     // in_ch
#define OO 32     // out_ch
#define II 32     // in_dim
#define JJ 32     // out_dim
#define MM (NN*CC)  // 2048 input capsules per (b, out_ch)
static constexpr float EPS_SQ = 1e-11f;

// Workspace (floats):
//   bij [BB][OO][CC][NN]  routing logits (m reordered to (c,n); softmax is
//                         permutation-invariant over m so this is safe)
//   mx  [BB][OO]          row max for softmax
//   rinv[BB][OO]          1/rowsum for softmax
//   cx  [BB][CC][OO][II]  softmax-weighted x: sum_n c * x
//
// Iteration 1's softmax of zeros is uniform 1/2048 -> k_cx uniform flag;
// no memset, no stats kernel for iter 1. bij is first WRITTEN (not +=) by
// the fused kernel (accum=0), which also computes softmax stats for the
// next iteration in-register (block owns the whole 2048-long row).
//
// v is NEVER materialized in global memory: squash and the agreement
// update are fused into one block-per-(b,o) kernel (they share the same
// grid decomposition, and the update only needs v[b,o,:]).

// XCD-affinity decode: same-b blocks land on the same XCD (blockIdx%8
// heuristic) so x[b] (256 KB) stays in that XCD's 4 MB L2.
__device__ inline void decode_bo(int bid, int& b, int& o) {
  int xcd = bid & 7, t = bid >> 3;
  b = xcd * 4 + (t & 3);
  o = t >> 2;
}

// ---- cx[b,c,o,i] = sum_n coef[o,n] * x[b,n,c,i];  block per (b,c) ----
__global__ __launch_bounds__(1024) void k_cx(
    const float* __restrict__ x, const float* __restrict__ bij,
    const float* __restrict__ mx, const float* __restrict__ rinv,
    float* __restrict__ cx, int uniform) {
  int b = blockIdx.x / CC, c = blockIdx.x % CC;
  __shared__ float coef[OO][NN];       // 16 KB
  __shared__ float xs[NN][II + 1];     // ~16.5 KB, +1 pad (conflict-free columns)
  int tid = threadIdx.x;
  #pragma unroll
  for (int k = 0; k < 4; ++k) {
    int idx = tid + k * 1024;          // = o*NN + n, coalesced in n
    int o = idx >> 7, n = idx & 127;
    int row = b * OO + o;
    coef[o][n] = uniform ? (1.0f / (float)MM)
                         : __expf(bij[((size_t)row * CC + c) * NN + n] - mx[row]) * rinv[row];
  }
  #pragma unroll
  for (int k = 0; k < 4; ++k) {
    int idx = tid + k * 1024;          // = n*II + i, coalesced in i
    int n = idx >> 5, i = idx & 31;
    xs[n][i] = x[(((size_t)b * NN + n) * CC + c) * II + i];
  }
  __syncthreads();
  int o = tid >> 5, i = tid & 31;
  float acc = 0.f;
  #pragma unroll 8
  for (int n = 0; n < NN; ++n) acc += coef[o][n] * xs[n][i];  // coef broadcast, xs padded
  cx[(((size_t)b * CC + c) * OO + o) * II + i] = acc;
}

// ---- FUSED squash + agreement update + softmax stats. Block per (b,o).
//   Phase A (squash): s[j] = sum_{c,i} cx[b,c,o,i]*W[c,o,i,j]; squash -> vs[] (LDS)
//   Phase B (update): wv[c,i] = sum_j W[c,o,i,j]*vs[j]
//     row[c,n] = (accum? bij : 0) + sum_i x[b,n,c,i]*wv[c,i]; write row,
//     then block-reduce max / sum-exp -> mx, rinv for the NEXT softmax. ----
__global__ __launch_bounds__(256) void k_squash_update(
    const float* __restrict__ cx, const float* __restrict__ W,
    const float* __restrict__ x, float* __restrict__ bij,
    float* __restrict__ mx, float* __restrict__ rinv, int accum) {
  int b, o; decode_bo(blockIdx.x, b, o);
  int tid = threadIdx.x, j = tid & 31, g = tid >> 5;   // 8 groups over c
  __shared__ float part[8][32];
  __shared__ float vs[JJ];             // 128 B, squashed v for THIS (b,o)
  __shared__ float wv[CC][II];         // 2 KB
  __shared__ float red[4], red2[4];

  // ---- Phase A: squash ----
  const float* cxb = cx + (size_t)b * CC * OO * II;
  float acc = 0.f;
  #pragma unroll
  for (int cc = 0; cc < 2; ++cc) {
    int c = g + cc * 8;
    #pragma unroll
    for (int i = 0; i < II; ++i) {
      // cx: broadcast across the 32 j-lanes; W: j-coalesced
      acc += cxb[(c * OO + o) * II + i] * W[(((size_t)c * OO + o) * II + i) * JJ + j];
    }
  }
  part[g][j] = acc;                    // 2-way-per-bank across wave: free
  __syncthreads();
  if (tid < 32) {
    float s = 0.f;
    #pragma unroll
    for (int gg = 0; gg < 8; ++gg) s += part[gg][j];
    float msq = s * s;
    #pragma unroll
    for (int off = 16; off > 0; off >>= 1) msq += __shfl_xor(msq, off);
    float mag = sqrtf(msq) + EPS_SQ;
    float a   = msq / (1.0f + msq);
    vs[j] = a * s / mag;               // v stays in LDS; never hits global
  }
  __syncthreads();

  // ---- Phase B: wv = W @ v ----
  #pragma unroll
  for (int k = 0; k < 2; ++k) {        // 512 wv entries / 256 threads
    int ci = tid + k * 256;
    int c = ci >> 5, i = ci & 31;
    const float4* Wr = (const float4*)(W + (((size_t)c * OO + o) * II + i) * JJ);
    float a2 = 0.f;
    #pragma unroll
    for (int q = 0; q < 8; ++q) {
      float4 w4 = Wr[q];
      a2 += w4.x * vs[q*4+0] + w4.y * vs[q*4+1] + w4.z * vs[q*4+2] + w4.w * vs[q*4+3];
    }
    wv[c][i] = a2;
  }
  __syncthreads();

  // ---- Phase B: row update + softmax stats for next iteration ----
  float* bp = bij + (size_t)(b * OO + o) * CC * NN;
  float vals[8];
  float m_ = -INFINITY;
  #pragma unroll
  for (int k = 0; k < 8; ++k) {        // 2048 row entries / 256 threads
    int m = tid + k * 256;
    int c = m >> 7, n = m & 127;
    const float4* xr = (const float4*)(x + (((size_t)b * NN + n) * CC + c) * II);
    float a3 = 0.f;
    #pragma unroll
    for (int q = 0; q < 8; ++q) {
      float4 x4 = xr[q];
      a3 += x4.x * wv[c][q*4+0] + x4.y * wv[c][q*4+1] + x4.z * wv[c][q*4+2] + x4.w * wv[c][q*4+3];
    }
    if (accum) a3 += bp[m];            // coalesced in n
    bp[m] = a3;
    vals[k] = a3;
    m_ = fmaxf(m_, a3);
  }
  #pragma unroll
  for (int off = 32; off > 0; off >>= 1) m_ = fmaxf(m_, __shfl_xor(m_, off));
  int wave = tid >> 6;
  if ((tid & 63) == 0) red[wave] = m_;
  __syncthreads();
  m_ = fmaxf(fmaxf(red[0], red[1]), fmaxf(red[2], red[3]));
  float s = 0.f;
  #pragma unroll
  for (int k = 0; k < 8; ++k) s += __expf(vals[k] - m_);
  #pragma unroll
  for (int off = 32; off > 0; off >>= 1) s += __shfl_xor(s, off);
  if ((tid & 63) == 0) red2[wave] = s;
  __syncthreads();
  if (tid == 0) {
    int row = b * OO + o;
    mx[row]   = m_;
    rinv[row] = 1.0f / (red2[0] + red2[1] + red2[2] + red2[3]);
  }
}

// ---- final squash only (iter 3 discards the last b_ij update) ----
__global__ __launch_bounds__(256) void k_squash_final(
    const float* __restrict__ cx, const float* __restrict__ W,
    float* __restrict__ out) {
  int b, o; decode_bo(blockIdx.x, b, o);
  int tid = threadIdx.x, j = tid & 31, g = tid >> 5;
  const float* cxb = cx + (size_t)b * CC * OO * II;
  float acc = 0.f;
  #pragma unroll
  for (int cc = 0; cc < 2; ++cc) {
    int c = g + cc * 8;
    #pragma unroll
    for (int i = 0; i < II; ++i) {
      acc += cxb[(c * OO + o) * II + i] * W[(((size_t)c * OO + o) * II + i) * JJ + j];
    }
  }
  __shared__ float part[8][32];
  part[g][j] = acc;
  __syncthreads();
  if (tid < 32) {
    float s = 0.f;
    #pragma unroll
    for (int gg = 0; gg < 8; ++gg) s += part[gg][j];
    float msq = s * s;
    #pragma unroll
    for (int off = 16; off > 0; off >>= 1) msq += __shfl_xor(msq, off);
    float mag = sqrtf(msq) + EPS_SQ;
    float a   = msq / (1.0f + msq);
    float vv  = a * s / mag;
    int row = b * OO + o;
    out[(size_t)row * JJ + j] = vv;                   // v_j: [B,1,O,J] flat
    if (j == 0) out[BB * OO * JJ + row] = a;          // a_j: [B,1,O,1] flat
  }
}

extern "C" void kernel_launch(void* const* d_in, const int* in_sizes, int n_in,
                              void* d_out, int out_size, void* d_ws, size_t ws_size,
                              hipStream_t stream) {
  const float* x = (const float*)d_in[0];   // [B,N,C,I]
  const float* W = (const float*)d_in[1];   // [C,O,I,J]
  (void)in_sizes; (void)n_in;               // d_in[2] = number_of_nodes (fixed 128)
  float* out = (float*)d_out; (void)out_size;

  float* ws   = (float*)d_ws;
  float* bij  = ws;                                   // 2,097,152 floats (8 MB)
  float* mx   = bij + (size_t)BB * OO * CC * NN;      // 1024
  float* rinv = mx + BB * OO;                         // 1024
  float* cx   = rinv + BB * OO;                       // 524,288 (2 MB)
  (void)ws_size;  // total ~10.1 MB

  // iter 1 (uniform softmax — bij rows are all zero)
  k_cx<<<BB * CC, 1024, 0, stream>>>(x, bij, mx, rinv, cx, 1);
  k_squash_update<<<BB * OO, 256, 0, stream>>>(cx, W, x, bij, mx, rinv, 0);
  // iter 2
  k_cx<<<BB * CC, 1024, 0, stream>>>(x, bij, mx, rinv, cx, 0);
  k_squash_update<<<BB * OO, 256, 0, stream>>>(cx, W, x, bij, mx, rinv, 1);
  // iter 3 (final; reference discards the last b_ij update)
  k_cx<<<BB * CC, 1024, 0, stream>>>(x, bij, mx, rinv, cx, 0);
  k_squash_final<<<BB * OO, 256, 0, stream>>>(cx, W, out);
}

// Round 2
// 128.479 us; speedup vs baseline: 1.4281x; 1.4281x over previous
//
#include <hip/hip_runtime.h>
#include <math.h>

// Problem constants (fixed by the reference):
#define BB 32     // batch
#define NN 128    // nodes
#define CC 16     // in_ch
#define OO 32     // out_ch
#define II 32     // in_dim
#define JJ 32     // out_dim
#define MM (NN*CC)  // 2048 input capsules per (b, out_ch)
#define NP (NN+4)   // padded LDS row: 16B-aligned rows, structural-min banks for b128
static constexpr float EPS_SQ = 1e-11f;

// Workspace (floats):
//   bij [BB][OO][CC][NN]  routing logits ((c,n) order; softmax is permutation-
//                         invariant over the 2048-long capsule dim, so safe)
//   mx  [BB][OO]          row max for softmax
//   rinv[BB][OO]          1/rowsum for softmax
//   cx  [BB][CC][OO][II]  softmax-weighted x
//   xT  [BB][CC][II][NN]  transposed x (built once by k_cx_first) so that the
//                         agreement update reads are lane-coalesced in n
//
// v never touches global memory (squash fused with the agreement update).
// All blocks are 1024 threads -> 2 blocks/CU, 32 waves/CU (full occupancy).

__device__ inline void decode_bo(int bid, int& b, int& o) {
  int xcd = bid & 7, t = bid >> 3;
  b = xcd * 4 + (t & 3);
  o = t >> 2;
}

// ---- iter-1 cx + x transpose. Uniform softmax (bij==0) makes
//      cx[b,c,o,i] = (1/MM) * sum_n x[b,n,c,i]  -- independent of o. ----
__global__ __launch_bounds__(1024, 8) void k_cx_first(
    const float* __restrict__ x, float* __restrict__ xT,
    float* __restrict__ cx) {
  int b = blockIdx.x / CC, c = blockIdx.x % CC;
  __shared__ float xsT[II][NP];        // ~16.9 KB
  __shared__ float rs[II];
  int tid = threadIdx.x;
  {
    int n = tid >> 3, i4 = (tid & 7) * 4;
    const float4 v = *(const float4*)(x + ((((size_t)b * NN + n) * CC + c) * II + i4));
    xsT[i4 + 0][n] = v.x; xsT[i4 + 1][n] = v.y;
    xsT[i4 + 2][n] = v.z; xsT[i4 + 3][n] = v.w;
  }
  __syncthreads();
  // write xT[b,c,i,n] (contiguous 16 KB per block, fully coalesced)
  float* xTp = xT + ((size_t)b * CC + c) * II * NN;
  #pragma unroll
  for (int k = 0; k < 4; ++k) {
    int idx = tid + k * 1024;
    int i = idx >> 7, n = idx & 127;
    xTp[idx] = xsT[i][n];
  }
  if (tid < II) {
    const float4* xr4 = (const float4*)(&xsT[tid][0]);
    float s = 0.f;
    #pragma unroll
    for (int nq = 0; nq < NN / 4; ++nq) {
      float4 v = xr4[nq];
      s += v.x; s += v.y; s += v.z; s += v.w;
    }
    rs[tid] = s * (1.0f / (float)MM);
  }
  __syncthreads();
  int o = tid >> 5, i = tid & 31;
  cx[(((size_t)b * CC + c) * OO + o) * II + i] = rs[i];
}

// ---- cx[b,c,o,i] = sum_n coef[o,n] * x[b,n,c,i]; block per (b,c).
//      float4 LDS reads (b128) for both operands. ----
__global__ __launch_bounds__(1024, 8) void k_cx(
    const float* __restrict__ xT, const float* __restrict__ bij,
    const float* __restrict__ mx, const float* __restrict__ rinv,
    float* __restrict__ cx) {
  int b = blockIdx.x / CC, c = blockIdx.x % CC;
  __shared__ float coef[OO][NN];       // 16 KB
  __shared__ float xsT[II][NP];        // ~16.9 KB
  int tid = threadIdx.x;
  #pragma unroll
  for (int k = 0; k < 4; ++k) {
    int idx = tid + k * 1024;          // = o*NN + n, coalesced in n
    int o = idx >> 7, n = idx & 127;
    int row = b * OO + o;
    coef[o][n] = __expf(bij[((size_t)row * CC + c) * NN + n] - mx[row]) * rinv[row];
  }
  {
    const float4* src = (const float4*)(xT + ((size_t)b * CC + c) * II * NN);
    float4 v = src[tid];               // contiguous 16 KB slice, coalesced
    int i = tid >> 5, n4 = (tid & 31) * 4;
    *(float4*)(&xsT[i][n4]) = v;       // rows 16B-aligned (NP=132)
  }
  __syncthreads();
  int o = tid >> 5, i = tid & 31;
  const float4* cf4 = (const float4*)(coef[o]);
  const float4* xr4 = (const float4*)(&xsT[i][0]);
  float acc = 0.f;
  #pragma unroll
  for (int nq = 0; nq < NN / 4; ++nq) {
    float4 cf = cf4[nq], xv = xr4[nq];
    acc += cf.x * xv.x; acc += cf.y * xv.y;
    acc += cf.z * xv.z; acc += cf.w * xv.w;
  }
  cx[(((size_t)b * CC + c) * OO + o) * II + i] = acc;
}

// ---- FUSED squash + agreement update + softmax stats. Block per (b,o).
//   Phase A: s[j] = sum_{c,i} cx[b,c,o,i]*W[c,o,i,j]; squash -> vs[] (LDS)
//   Phase W: wv[c,i] = sum_j W[c,o,i,j]*vs[j]
//   Phase B: row[c,n] = (accum? bij:0) + sum_i xT[b,c,i,n]*wv[c,i]
//            (coalesced in n); then block max / sum-exp -> mx, rinv. ----
__global__ __launch_bounds__(1024, 8) void k_squash_update(
    const float* __restrict__ cx, const float* __restrict__ W,
    const float* __restrict__ xT, float* __restrict__ bij,
    float* __restrict__ mx, float* __restrict__ rinv, int accum) {
  int b, o; decode_bo(blockIdx.x, b, o);
  int tid = threadIdx.x;
  __shared__ float part[32][32];       // 4 KB
  __shared__ float vs[JJ];
  __shared__ float wvp[CC * II][2];    // 4 KB
  __shared__ float wv[CC * II];        // 2 KB
  __shared__ float red[16], red2[16];

  // ---- Phase A ----
  {
    int j = tid & 31, g = tid >> 5;    // 32 groups over (c, i-half)
    int c = g >> 1, i0 = (g & 1) * 16;
    const float* cxp = cx + (((size_t)b * CC + c) * OO + o) * II + i0;
    const float* Wp  = W + ((((size_t)c * OO + o) * II + i0) * JJ) + j;
    float acc = 0.f;
    #pragma unroll
    for (int i = 0; i < 16; ++i) acc += cxp[i] * Wp[i * JJ];  // W j-coalesced
    part[g][j] = acc;
  }
  __syncthreads();
  if (tid < 32) {                       // j = tid
    float s = 0.f;
    #pragma unroll
    for (int g = 0; g < 32; ++g) s += part[g][tid];  // distinct banks per lane
    float msq = s * s;
    #pragma unroll
    for (int off = 16; off > 0; off >>= 1) msq += __shfl_xor(msq, off);
    float mag = sqrtf(msq) + EPS_SQ;
    float a   = msq / (1.0f + msq);
    vs[tid] = a * s / mag;
  }
  __syncthreads();

  // ---- Phase W: wv = W @ v ----
  {
    int ci = tid >> 1, jh = tid & 1;   // 512 (c,i) x 2 j-halves
    int c = ci >> 5, i = ci & 31;
    const float4* Wr = (const float4*)(W + ((((size_t)c * OO + o) * II + i) * JJ) + jh * 16);
    float a2 = 0.f;
    #pragma unroll
    for (int q = 0; q < 4; ++q) {
      float4 w4 = Wr[q];
      int jb = jh * 16 + q * 4;
      a2 += w4.x * vs[jb] + w4.y * vs[jb + 1] + w4.z * vs[jb + 2] + w4.w * vs[jb + 3];
    }
    wvp[ci][jh] = a2;
  }
  __syncthreads();
  if (tid < CC * II) wv[tid] = wvp[tid][0] + wvp[tid][1];
  __syncthreads();

  // ---- Phase B: two rows per thread, same c (one wv broadcast feeds both) ----
  const float* xTb = xT + (size_t)b * CC * II * NN;
  float* bp = bij + ((size_t)(b * OO + o)) * CC * NN;
  int c = tid >> 6, n = tid & 63;      // rows (c,n) and (c,n+64)
  const float* xc  = xTb + (size_t)c * II * NN + n;
  const float* wvc = wv + c * II;
  float a0 = 0.f, a1 = 0.f;
  #pragma unroll
  for (int i = 0; i < II; ++i) {
    float wvv = wvc[i];                // wave-uniform LDS broadcast
    a0 += xc[i * NN] * wvv;            // lane-coalesced in n
    a1 += xc[i * NN + 64] * wvv;
  }
  int m0 = c * NN + n, m1 = m0 + 64;
  if (accum) { a0 += bp[m0]; a1 += bp[m1]; }
  bp[m0] = a0; bp[m1] = a1;
  float m_ = fmaxf(a0, a1);
  #pragma unroll
  for (int off = 32; off > 0; off >>= 1) m_ = fmaxf(m_, __shfl_xor(m_, off));
  int wave = tid >> 6;
  if ((tid & 63) == 0) red[wave] = m_;
  __syncthreads();
  float mAll = red[0];
  #pragma unroll
  for (int w = 1; w < 16; ++w) mAll = fmaxf(mAll, red[w]);
  float s = __expf(a0 - mAll) + __expf(a1 - mAll);
  #pragma unroll
  for (int off = 32; off > 0; off >>= 1) s += __shfl_xor(s, off);
  if ((tid & 63) == 0) red2[wave] = s;
  __syncthreads();
  if (tid == 0) {
    float ss = 0.f;
    #pragma unroll
    for (int w = 0; w < 16; ++w) ss += red2[w];
    int row = b * OO + o;
    mx[row]   = mAll;
    rinv[row] = 1.0f / ss;
  }
}

// ---- final squash only (iter 3 discards the last b_ij update) ----
__global__ __launch_bounds__(1024, 8) void k_squash_final(
    const float* __restrict__ cx, const float* __restrict__ W,
    float* __restrict__ out) {
  int b, o; decode_bo(blockIdx.x, b, o);
  int tid = threadIdx.x;
  __shared__ float part[32][32];
  {
    int j = tid & 31, g = tid >> 5;
    int c = g >> 1, i0 = (g & 1) * 16;
    const float* cxp = cx + (((size_t)b * CC + c) * OO + o) * II + i0;
    const float* Wp  = W + ((((size_t)c * OO + o) * II + i0) * JJ) + j;
    float acc = 0.f;
    #pragma unroll
    for (int i = 0; i < 16; ++i) acc += cxp[i] * Wp[i * JJ];
    part[g][j] = acc;
  }
  __syncthreads();
  if (tid < 32) {
    float s = 0.f;
    #pragma unroll
    for (int g = 0; g < 32; ++g) s += part[g][tid];
    float msq = s * s;
    #pragma unroll
    for (int off = 16; off > 0; off >>= 1) msq += __shfl_xor(msq, off);
    float mag = sqrtf(msq) + EPS_SQ;
    float a   = msq / (1.0f + msq);
    float vv  = a * s / mag;
    int row = b * OO + o;
    out[(size_t)row * JJ + tid] = vv;                 // v_j: [B,1,O,J] flat
    if (tid == 0) out[BB * OO * JJ + row] = a;        // a_j: [B,1,O,1] flat
  }
}

extern "C" void kernel_launch(void* const* d_in, const int* in_sizes, int n_in,
                              void* d_out, int out_size, void* d_ws, size_t ws_size,
                              hipStream_t stream) {
  const float* x = (const float*)d_in[0];   // [B,N,C,I]
  const float* W = (const float*)d_in[1];   // [C,O,I,J]
  (void)in_sizes; (void)n_in;               // d_in[2] = number_of_nodes (fixed 128)
  float* out = (float*)d_out; (void)out_size;

  float* ws   = (float*)d_ws;
  float* bij  = ws;                                   // 2,097,152 floats (8 MB)
  float* mx   = bij + (size_t)BB * OO * CC * NN;      // 1024
  float* rinv = mx + BB * OO;                         // 1024
  float* cx   = rinv + BB * OO;                       // 524,288 (2 MB)
  float* xT   = cx + (size_t)BB * CC * OO * II;       // 2,097,152 (8 MB)
  (void)ws_size;  // total ~18.1 MB

  // iter 1 (uniform softmax; also builds xT)
  k_cx_first<<<BB * CC, 1024, 0, stream>>>(x, xT, cx);
  k_squash_update<<<BB * OO, 1024, 0, stream>>>(cx, W, xT, bij, mx, rinv, 0);
  // iter 2
  k_cx<<<BB * CC, 1024, 0, stream>>>(xT, bij, mx, rinv, cx);
  k_squash_update<<<BB * OO, 1024, 0, stream>>>(cx, W, xT, bij, mx, rinv, 1);
  // iter 3 (final; reference discards the last b_ij update)
  k_cx<<<BB * CC, 1024, 0, stream>>>(xT, bij, mx, rinv, cx);
  k_squash_final<<<BB * OO, 1024, 0, stream>>>(cx, W, out);
}